// Round 6
// baseline (51.877 us; speedup 1.0000x reference)
//
#include <hip/hip_runtime.h>

// Camera ISP fused: mosaic -> 3x3 gauss blur -> 17-knot LUT -> +noise ->
// sparse 5x5 demosaic -> bayer-parity select -> clip.
// Round 5: wave-private tiles. Each wave owns a 64x16 output tile + private
// LDS noisy buffer; ZERO __syncthreads. 128-thread blocks (2 stacked waves).
// Wave-synchronous LDS ordering via s_waitcnt lgkmcnt(0) (wave ops in-order).

#define NROWS 20       // noisy rows per wave tile: gy0-2 .. gy0+17
#define NSTR  76       // 76%32=12 -> conflict-free stage C

typedef float f4u __attribute__((ext_vector_type(4), aligned(4)));

__device__ __forceinline__ int refl(int i, int n) {
    return i < 0 ? -i : (i >= n ? 2 * n - 2 - i : i);
}

__device__ __forceinline__ float clip01(float x) {
    return fminf(fmaxf(x * (1.0f / 255.0f), 0.0f), 1.0f);
}

__global__ __launch_bounds__(128, 6) void camera_kernel(
    const float* __restrict__ im, const float* __restrict__ yp,
    const float* __restrict__ noise, float* __restrict__ out,
    int H, int W)
{
    __shared__ float  s_noisy[2][NROWS * NSTR];   // 12160 B (wave-private halves)
    __shared__ float2 s_tab[2][3][16];            // 768 B  (per-wave copies)

    const int wv   = threadIdx.x >> 6;
    const int lane = threadIdx.x & 63;
    const int b    = blockIdx.z;
    // y-tiles iterate fastest (blockIdx.x) so vertical neighbors are
    // dispatch-adjacent -> shared mosaic halo rows hit L2 on the same XCD.
    const int gy0  = blockIdx.x * 32 + wv * 16;   // wave tile origin (even)
    const int gx0  = blockIdx.y * 64;             // even

    const size_t HW = (size_t)H * W;
    const float* p0  = im + (size_t)b * 3 * HW;   // ch0
    const float* p1  = p0 + HW;                    // ch1
    const float* p2  = p1 + HW;                    // ch2
    const float* nzb = noise + (size_t)b * HW;

    if (lane < 48) {
        int ch = lane >> 4, i = lane & 15;
        s_tab[wv][ch][i] = make_float2(yp[ch * 17 + i], yp[ch * 17 + i + 1]);
    }
    asm volatile("s_waitcnt lgkmcnt(0)" ::: "memory");   // tab visible wave-wide

    float* sn = s_noisy[wv];
    const float2 (*tab)[16] = s_tab[wv];

    const float g0 = 0.04038794f;   // 1D gauss tail (sigma=0.4, normalized)
    const float g1 = 0.91922413f;   // 1D gauss center

    // ---- Stage B: noisy row-pairs = interp(blur(mosaic)) + noise ----
    // 10 row-pairs x 18 col4-sites = 180 sites per wave; 3 lane-iterations.
    #pragma unroll
    for (int s = 0; s < 3; ++s) {
        int idx = lane + 64 * s;
        if (idx < 180) {
            int rp = idx / 18, c4 = idx - rp * 18;
            int py0 = gy0 - 2 + 2 * rp;           // even row of the pair
            int x0  = gx0 - 4 + 4 * c4;           // first output col (even)
            int ya = refl(py0 - 1, H);            // odd row
            int yb = refl(py0,     H);            // even row
            int yc = refl(py0 + 1, H);            // odd row
            int yd = refl(py0 + 2, H);            // even row

            float t0[6], t1[6];
            if (x0 >= 1 && x0 <= W - 5) {
                #define LDMOS(podd, peven, yy, m)                             \
                    {                                                         \
                        const float* pa = (podd)  + (size_t)(yy) * W;         \
                        const float* pb = (peven) + (size_t)(yy) * W;         \
                        f4u alo = *(const f4u*)(pa + x0 - 1);                 \
                        f4u ahi = *(const f4u*)(pa + x0 + 1);                 \
                        f4u blo = *(const f4u*)(pb + x0 - 1);                 \
                        f4u bhi = *(const f4u*)(pb + x0 + 1);                 \
                        m[0] = alo.x; m[1] = blo.y; m[2] = alo.z;             \
                        m[3] = blo.w; m[4] = ahi.z; m[5] = bhi.w;             \
                    }
                float m[6];
                LDMOS(p1, p0, ya, m);             // row ya (odd)
                #pragma unroll
                for (int j = 0; j < 6; ++j) t0[j] = g0 * m[j];
                LDMOS(p2, p1, yb, m);             // row yb (even)
                #pragma unroll
                for (int j = 0; j < 6; ++j) { t0[j] = fmaf(g1, m[j], t0[j]); t1[j] = g0 * m[j]; }
                LDMOS(p1, p0, yc, m);             // row yc (odd)
                #pragma unroll
                for (int j = 0; j < 6; ++j) { t0[j] = fmaf(g0, m[j], t0[j]); t1[j] = fmaf(g1, m[j], t1[j]); }
                LDMOS(p2, p1, yd, m);             // row yd (even)
                #pragma unroll
                for (int j = 0; j < 6; ++j) t1[j] = fmaf(g0, m[j], t1[j]);
                #undef LDMOS
            } else {
                #pragma unroll
                for (int j = 0; j < 6; ++j) {
                    int xx = refl(x0 - 1 + j, W);  // parity preserved
                    bool oddc = (xx & 1) != 0;
                    size_t oa = (size_t)ya * W + xx, ob = (size_t)yb * W + xx;
                    size_t oc = (size_t)yc * W + xx, od = (size_t)yd * W + xx;
                    float a  = oddc ? p1[oa] : p0[oa];
                    float bq = oddc ? p2[ob] : p1[ob];
                    float cq = oddc ? p1[oc] : p0[oc];
                    float dq = oddc ? p2[od] : p1[od];
                    t0[j] = fmaf(g0, a + cq,  g1 * bq);
                    t1[j] = fmaf(g0, bq + dq, g1 * cq);
                }
            }

            float4 nz0, nz1;
            if (x0 >= 0 && x0 + 3 < W) {
                nz0 = *(const float4*)(nzb + (size_t)yb * W + x0);
                nz1 = *(const float4*)(nzb + (size_t)yc * W + x0);
            } else {
                const float* n0 = nzb + (size_t)yb * W;
                const float* n1 = nzb + (size_t)yc * W;
                int xa = refl(x0, W), xb2 = refl(x0 + 1, W),
                    xc2 = refl(x0 + 2, W), xd2 = refl(x0 + 3, W);
                nz0 = make_float4(n0[xa], n0[xb2], n0[xc2], n0[xd2]);
                nz1 = make_float4(n1[xa], n1[xb2], n1[xc2], n1[xd2]);
            }

            float o0[4], o1[4];
            #pragma unroll
            for (int i = 0; i < 4; ++i) {
                float s0 = fmaf(g0, t0[i] + t0[i + 2], g1 * t0[i + 1]) * 16.0f;
                float s1 = fmaf(g0, t1[i] + t1[i + 2], g1 * t1[i + 1]) * 16.0f;
                int i0 = (int)s0; i0 = i0 > 15 ? 15 : (i0 < 0 ? 0 : i0);
                int i1 = (int)s1; i1 = i1 > 15 ? 15 : (i1 < 0 ? 0 : i1);
                float2 pa = tab[(i & 1) ? 2 : 1][i0];   // even row: ch1/ch2
                float2 pb = tab[(i & 1) ? 1 : 0][i1];   // odd row:  ch0/ch1
                o0[i] = fmaf(s0 - (float)i0, pa.y - pa.x, pa.x);
                o1[i] = fmaf(s1 - (float)i1, pb.y - pb.x, pb.x);
            }
            *(f4u*)&sn[(2 * rp) * NSTR + 4 * c4] =
                (f4u){o0[0] + nz0.x, o0[1] + nz0.y, o0[2] + nz0.z, o0[3] + nz0.w};
            *(f4u*)&sn[(2 * rp + 1) * NSTR + 4 * c4] =
                (f4u){o1[0] + nz1.x, o1[1] + nz1.y, o1[2] + nz1.z, o1[3] + nz1.w};
        }
    }
    asm volatile("s_waitcnt lgkmcnt(0)" ::: "memory");   // wave's noisy complete

    // ---- Stage C: demosaic, 2 iterations x (2 rows x 4 cols) per lane ----
    const int rpl = lane >> 4;    // 0..3
    const int c4  = lane & 15;    // 0..15
    const size_t outb = (size_t)b * 3 * HW;

    auto dem = [](const float (&up)[12], const float (&ct)[12], const float (&dn)[12],
                  const float* u2, const float* d2, bool rowOdd,
                  float* R, float* G, float* Bv) {
        #pragma unroll
        for (int i = 0; i < 4; ++i) {
            float c    = ct[4 + i];
            float ax1x = ct[3 + i] + ct[5 + i];
            float ax2x = ct[2 + i] + ct[6 + i];
            float ax1y = up[4 + i] + dn[4 + i];
            float diag = up[3 + i] + up[5 + i] + dn[3 + i] + dn[5 + i];
            float ax2y = u2[i] + d2[i];
            const bool xOdd = (i & 1) != 0;
            if (!xOdd && !rowOdd) {          // p00: R=v, G=raw, B=h
                float h = (0.5f * ax2y - diag - ax2x + 4.0f * ax1x + 5.0f * c) * 0.125f;
                float v = (0.5f * ax2x - diag - ax2y + 4.0f * ax1y + 5.0f * c) * 0.125f;
                R[i] = v; G[i] = c; Bv[i] = h;
            } else if (xOdd && !rowOdd) {    // p01: R=d, G=g, B=raw
                float g = (2.0f * (ax1y + ax1x) - ax2y - ax2x + 4.0f * c) * 0.125f;
                float d = (2.0f * diag - 1.5f * (ax2y + ax2x) + 6.0f * c) * 0.125f;
                R[i] = d; G[i] = g; Bv[i] = c;
            } else if (!xOdd && rowOdd) {    // p10: R=raw, G=g, B=d
                float g = (2.0f * (ax1y + ax1x) - ax2y - ax2x + 4.0f * c) * 0.125f;
                float d = (2.0f * diag - 1.5f * (ax2y + ax2x) + 6.0f * c) * 0.125f;
                R[i] = c; G[i] = g; Bv[i] = d;
            } else {                         // p11: R=h, G=raw, B=v
                float h = (0.5f * ax2y - diag - ax2x + 4.0f * ax1x + 5.0f * c) * 0.125f;
                float v = (0.5f * ax2x - diag - ax2y + 4.0f * ax1y + 5.0f * c) * 0.125f;
                R[i] = h; G[i] = c; Bv[i] = v;
            }
        }
    };

    #pragma unroll
    for (int it = 0; it < 2; ++it) {
        int rp = rpl + 4 * it;               // 0..7 row-pairs in this wave tile
        int nbase = (2 * rp + 2) * NSTR + 4 * c4;
        float w[4][12];                      // noisy rows 2rp+1 .. 2rp+4
        #pragma unroll
        for (int rr = 0; rr < 4; ++rr) {
            const float* p = &sn[nbase + (rr - 1) * NSTR];
            *(f4u*)&w[rr][0] = *(const f4u*)(p);
            *(f4u*)&w[rr][4] = *(const f4u*)(p + 4);
            *(f4u*)&w[rr][8] = *(const f4u*)(p + 8);
        }
        f4u c2u = *(const f4u*)&sn[nbase - 2 * NSTR + 4];  // row 2rp centers
        f4u c2d = *(const f4u*)&sn[nbase + 3 * NSTR + 4];  // row 2rp+5 centers
        float cu[4] = {c2u.x, c2u.y, c2u.z, c2u.w};
        float cd[4] = {c2d.x, c2d.y, c2d.z, c2d.w};

        float R0[4], G0[4], B0[4], R1[4], G1[4], B1[4];
        dem(w[0], w[1], w[2], cu,       &w[3][4], false, R0, G0, B0);  // even row
        dem(w[1], w[2], w[3], &w[0][4], cd,       true,  R1, G1, B1);  // odd row

        int py = gy0 + 2 * rp;
        size_t o = outb + (size_t)py * W + (gx0 + 4 * c4);
        *(float4*)(out + o) = make_float4(clip01(R0[0]), clip01(R0[1]), clip01(R0[2]), clip01(R0[3]));
        *(float4*)(out + o + HW) = make_float4(clip01(G0[0]), clip01(G0[1]), clip01(G0[2]), clip01(G0[3]));
        *(float4*)(out + o + 2 * HW) = make_float4(clip01(B0[0]), clip01(B0[1]), clip01(B0[2]), clip01(B0[3]));
        o += W;
        *(float4*)(out + o) = make_float4(clip01(R1[0]), clip01(R1[1]), clip01(R1[2]), clip01(R1[3]));
        *(float4*)(out + o + HW) = make_float4(clip01(G1[0]), clip01(G1[1]), clip01(G1[2]), clip01(G1[3]));
        *(float4*)(out + o + 2 * HW) = make_float4(clip01(B1[0]), clip01(B1[1]), clip01(B1[2]), clip01(B1[3]));
    }
}

extern "C" void kernel_launch(void* const* d_in, const int* in_sizes, int n_in,
                              void* d_out, int out_size, void* d_ws, size_t ws_size,
                              hipStream_t stream) {
    const float* im    = (const float*)d_in[0];
    const float* yp    = (const float*)d_in[1];
    const float* noise = (const float*)d_in[2];
    float* out = (float*)d_out;

    const int H = 512, W = 512;
    const int B = in_sizes[2] / (H * W);   // noise is (B,1,H,W)

    // y-tiles on grid.x (fastest) for vertical-halo L2 locality
    dim3 grid(H / 32, W / 64, B);
    camera_kernel<<<grid, 128, 0, stream>>>(im, yp, noise, out, H, W);
}

// Round 7
// 42.770 us; speedup vs baseline: 1.2129x; 1.2129x over previous
//
#include <hip/hip_runtime.h>

// Camera ISP fused: mosaic -> 3x3 gauss blur -> 17-knot LUT -> +noise ->
// sparse 5x5 demosaic -> bayer-parity select -> clip.
// Round 6: rolling-register pipeline. Wave = 256-wide x 16-row stripe.
// 5-row noisy ring + 2-row hblur ring in REGISTERS (full unroll, static
// indices). No LDS data buffers, no barriers. Each mosaic/noise row loaded
// once, aligned. Horizontal halo via __shfl; wave-edge lanes compute halo.

#define TDS 16     // output rows per wave

typedef float f4u __attribute__((ext_vector_type(4), aligned(16)));

struct HB { float hb0, hb1, hb2, hb3, hh0, hh1; };

__device__ __forceinline__ int refl(int i, int n) {
    return i < 0 ? -i : (i >= n ? 2 * n - 2 - i : i);
}

__device__ __forceinline__ float clip01(float x) {
    return fminf(fmaxf(x * (1.0f / 255.0f), 0.0f), 1.0f);
}

__global__ __launch_bounds__(256, 2) void camera_kernel(
    const float* __restrict__ im, const float* __restrict__ yp,
    const float* __restrict__ noise, float* __restrict__ out,
    int H, int W)
{
    __shared__ float2 s_tab[4][48];   // per-wave LUT copy (no block barrier)

    const int tid  = threadIdx.x;
    const int wv   = tid >> 6;
    const int lane = tid & 63;
    const int b    = blockIdx.z;

    const int stripes = W >> 8;                  // 256-px stripes
    const int slot    = blockIdx.x * 4 + wv;
    const int stripe  = slot % stripes;
    const int gy0     = (slot / stripes) * TDS;  // even
    const int gx0     = stripe << 8;             // even
    const int x0      = gx0 + 4 * lane;

    const size_t HW = (size_t)H * W;
    const float* p0  = im + (size_t)b * 3 * HW;  // ch0 plane
    const float* p1  = p0 + HW;                  // ch1 plane
    const float* nzb = noise + (size_t)b * HW;

    if (lane < 48) {
        int ch = lane >> 4, i = lane & 15;
        s_tab[wv][lane] = make_float2(yp[ch * 17 + i], yp[ch * 17 + i + 1]);
    }
    asm volatile("s_waitcnt lgkmcnt(0)" ::: "memory");
    const float2* tabw = s_tab[wv];

    const bool l0   = (lane == 0), l63 = (lane == 63);
    const bool lInt = l0  && (gx0 != 0);         // interior stripe boundary
    const bool rInt = l63 && (x0 + 4 != W);
    const bool eInt = lInt || rInt;
    const bool eAny = l0 || l63;
    const int  xe   = l0 ? x0 - 4 : x0 + 4;      // edge mosaic halo base
    const int  xen  = l0 ? x0 - 2 : x0 + 4;      // edge noise halo base

    const float g0 = 0.04038794f;   // 1D gauss tail (sigma=0.4, normalized)
    const float g1 = 0.91922413f;   // 1D gauss center

    auto itp = [&](float tv, int ch) -> float {  // LUT interp, input x16 scale
        float s = tv * 16.0f;
        int i = (int)s; i = i < 0 ? 0 : (i > 15 ? 15 : i);
        float2 p = tabw[ch * 16 + i];
        return fmaf(s - (float)i, p.y - p.x, p.x);
    };

    // load mosaic row t (reflect-mapped), return hblur[x0..x0+3] + edge halo
    auto mosrow = [&](int t) -> HB {
        int yr = refl(t, H);                     // parity-preserving
        const float* pe = (t & 1) ? p0 : p1;     // plane for even cols
        const float* re = pe + (size_t)yr * W;
        const float* ro = re + HW;               // plane for odd cols
        f4u a  = *(const f4u*)(re + x0);
        f4u bq = *(const f4u*)(ro + x0);
        float m0 = a.x, m1 = bq.y, m2 = a.z, m3 = bq.w;  // cols x0..x0+3
        float ml = __shfl_up(m3, 1, 64);         // col x0-1 (from lane-1)
        float mr = __shfl_down(m0, 1, 64);       // col x0+4 (from lane+1)
        float me0 = 0.f, me1 = 0.f, me2 = 0.f, me3 = 0.f;
        if (eInt) {                              // neighbor-stripe 4 cols
            f4u ae = *(const f4u*)(re + xe);
            f4u be = *(const f4u*)(ro + xe);
            me0 = ae.x; me1 = be.y; me2 = ae.z; me3 = be.w;
        }
        if (l0)  ml = lInt ? me3 : m1;           // reflect: col -1 -> 1
        if (l63) mr = rInt ? me0 : m2;           // reflect: col W -> W-2
        HB h;
        h.hb0 = fmaf(g0, ml + m1, g1 * m0);
        h.hb1 = fmaf(g0, m0 + m2, g1 * m1);
        h.hb2 = fmaf(g0, m1 + m3, g1 * m2);
        h.hb3 = fmaf(g0, m2 + mr, g1 * m3);
        // edge-halo hblur (lane0: cols x0-2,x0-1 ; lane63: cols x0+4,x0+5)
        float hL0 = fmaf(g0, me1 + me3, g1 * me2);
        float hL1 = fmaf(g0, me2 + m0,  g1 * me3);
        float hR0 = fmaf(g0, m3 + me1,  g1 * me0);
        float hR1 = fmaf(g0, me0 + me2, g1 * me1);
        h.hh0 = l0 ? hL0 : hR0;
        h.hh1 = l0 ? hL1 : hR1;
        return h;
    };

    float ring[5][8];                            // 5 noisy rows x cols x0-2..x0+5
    HB hA = mosrow(gy0 - 3);
    HB hB = mosrow(gy0 - 2);
    const size_t outb = (size_t)b * 3 * HW;

    #pragma unroll
    for (int k = 0; k < TDS + 4; ++k) {
        const int r = gy0 - 2 + k;               // noisy row produced this iter
        HB hC = mosrow(r + 1);
        // vertical blur (rows r-1, r, r+1)
        float tb0 = fmaf(g0, hA.hb0 + hC.hb0, g1 * hB.hb0);
        float tb1 = fmaf(g0, hA.hb1 + hC.hb1, g1 * hB.hb1);
        float tb2 = fmaf(g0, hA.hb2 + hC.hb2, g1 * hB.hb2);
        float tb3 = fmaf(g0, hA.hb3 + hC.hb3, g1 * hB.hb3);
        float th0 = fmaf(g0, hA.hh0 + hC.hh0, g1 * hB.hh0);
        float th1 = fmaf(g0, hA.hh1 + hC.hh1, g1 * hB.hh1);
        // LUT interp; row parity = k&1 (gy0 even)
        const int chE = (k & 1) ? 0 : 1;         // channel for even cols
        const int chO = chE + 1;
        float c0 = itp(tb0, chE), c1 = itp(tb1, chO);
        float c2 = itp(tb2, chE), c3 = itp(tb3, chO);
        // noise
        int yr = refl(r, H);
        const float* nzr = nzb + (size_t)yr * W;
        f4u nz = *(const f4u*)(nzr + x0);
        float2 nze = make_float2(0.f, 0.f);
        if (eInt) nze = *(const float2*)(nzr + xen);
        c0 += nz.x; c1 += nz.y; c2 += nz.z; c3 += nz.w;
        // edge-halo noisy (2 px, exec-masked to lanes 0/63)
        float e0 = 0.f, e1 = 0.f;
        if (eAny) { e0 = itp(th0, chE) + nze.x; e1 = itp(th1, chO) + nze.y; }
        // horizontal halo cols x0-2,x0-1 / x0+4,x0+5
        float hl0 = __shfl_up(c2, 1, 64);
        float hl1 = __shfl_up(c3, 1, 64);
        float hr0 = __shfl_down(c0, 1, 64);
        float hr1 = __shfl_down(c1, 1, 64);
        if (l0)  { hl0 = lInt ? e0 : c2;  hl1 = lInt ? e1 : c1; }  // reflect -2,-1 -> 2,1
        if (l63) { hr0 = rInt ? e0 : c2;  hr1 = rInt ? e1 : c1; }  // reflect W,W+1 -> W-2,W-3
        ring[k % 5][0] = hl0; ring[k % 5][1] = hl1;
        ring[k % 5][2] = c0;  ring[k % 5][3] = c1;
        ring[k % 5][4] = c2;  ring[k % 5][5] = c3;
        ring[k % 5][6] = hr0; ring[k % 5][7] = hr1;
        hA = hB; hB = hC;

        if (k >= 4) {                            // demosaic row y = gy0+k-4
            const int y = gy0 + k - 4;           // parity = k&1
            float Rv[4], Gv[4], Bv[4];
            #pragma unroll
            for (int j = 0; j < 4; ++j) {
                const int cj = 2 + j;
                float c    = ring[(k - 2) % 5][cj];
                float ax1x = ring[(k - 2) % 5][cj - 1] + ring[(k - 2) % 5][cj + 1];
                float ax2x = ring[(k - 2) % 5][cj - 2] + ring[(k - 2) % 5][cj + 2];
                float ax1y = ring[(k - 3) % 5][cj] + ring[(k - 1) % 5][cj];
                float diag = ring[(k - 3) % 5][cj - 1] + ring[(k - 3) % 5][cj + 1]
                           + ring[(k - 1) % 5][cj - 1] + ring[(k - 1) % 5][cj + 1];
                float ax2y = ring[(k - 4) % 5][cj] + ring[k % 5][cj];
                const bool xO = (j & 1) != 0;
                const bool yO = (k & 1) != 0;
                float R, G, Bc;
                if (!yO && !xO) {        // p00: R=v, G=raw, B=h
                    float hh = (0.5f * ax2y - diag - ax2x + 4.f * ax1x + 5.f * c) * 0.125f;
                    float vv = (0.5f * ax2x - diag - ax2y + 4.f * ax1y + 5.f * c) * 0.125f;
                    R = vv; G = c; Bc = hh;
                } else if (!yO && xO) {  // p01: R=d, G=g, B=raw
                    float gg = (2.f * (ax1y + ax1x) - ax2y - ax2x + 4.f * c) * 0.125f;
                    float dd = (2.f * diag - 1.5f * (ax2y + ax2x) + 6.f * c) * 0.125f;
                    R = dd; G = gg; Bc = c;
                } else if (yO && !xO) {  // p10: R=raw, G=g, B=d
                    float gg = (2.f * (ax1y + ax1x) - ax2y - ax2x + 4.f * c) * 0.125f;
                    float dd = (2.f * diag - 1.5f * (ax2y + ax2x) + 6.f * c) * 0.125f;
                    R = c; G = gg; Bc = dd;
                } else {                 // p11: R=h, G=raw, B=v
                    float hh = (0.5f * ax2y - diag - ax2x + 4.f * ax1x + 5.f * c) * 0.125f;
                    float vv = (0.5f * ax2x - diag - ax2y + 4.f * ax1y + 5.f * c) * 0.125f;
                    R = hh; G = c; Bc = vv;
                }
                Rv[j] = clip01(R); Gv[j] = clip01(G); Bv[j] = clip01(Bc);
            }
            size_t o = outb + (size_t)y * W + x0;
            *(f4u*)(out + o)          = (f4u){Rv[0], Rv[1], Rv[2], Rv[3]};
            *(f4u*)(out + o + HW)     = (f4u){Gv[0], Gv[1], Gv[2], Gv[3]};
            *(f4u*)(out + o + 2 * HW) = (f4u){Bv[0], Bv[1], Bv[2], Bv[3]};
        }
    }
}

extern "C" void kernel_launch(void* const* d_in, const int* in_sizes, int n_in,
                              void* d_out, int out_size, void* d_ws, size_t ws_size,
                              hipStream_t stream) {
    const float* im    = (const float*)d_in[0];
    const float* yp    = (const float*)d_in[1];
    const float* noise = (const float*)d_in[2];
    float* out = (float*)d_out;

    const int H = 512, W = 512;
    const int B = in_sizes[2] / (H * W);         // noise is (B,1,H,W)

    const int stripes = W / 256;                 // 2
    const int slots   = stripes * (H / TDS);     // 64 wave-slots per image
    dim3 grid(slots / 4, 1, B);                  // 4 waves per 256-thread block
    camera_kernel<<<grid, 256, 0, stream>>>(im, yp, noise, out, H, W);
}